// Round 6
// baseline (525.224 us; speedup 1.0000x reference)
//
#include <hip/hip_runtime.h>
#include <math.h>

#define N_NODES 100000
#define N_EDGES 1600000
#define IN_F 512
#define HID 128
#define NCLS 7

#define DEG_SHIFT 43
#define DEG_WMASK ((1ull << 43) - 1)
#define DEG_SCALE 4194304.0f          // 2^22
#define DEG_INV_SCALE (1.0f / 4194304.0f)
#define NB_SCAN 98                    // ceil(100000 / 1024)
#define G_FILL 6250                   // N_EDGES / 256
#define G_GEMM 1563                   // ceil((N_NODES/16) / 4) waves-blocks
#define G_MERGED (G_FILL + G_GEMM)    // 7813

typedef short short8 __attribute__((ext_vector_type(8)));
typedef float f32x4 __attribute__((ext_vector_type(4)));
typedef unsigned long long u64;

__device__ __forceinline__ unsigned pack_bf16x2(float a, float b) {
  unsigned ua = __float_as_uint(a), ub = __float_as_uint(b);
  unsigned ra = (ua + 0x7FFFu + ((ua >> 16) & 1u)) >> 16;     // RNE
  unsigned rb = (ub + 0x7FFFu + ((ub >> 16) & 1u)) >> 16;
  return ra | (rb << 16);
}
__device__ __forceinline__ unsigned short f32_to_bf16(float v) {
  unsigned u = __float_as_uint(v);
  return (unsigned short)((u + 0x7FFFu + ((u >> 16) & 1u)) >> 16);
}
__device__ __forceinline__ float bf_lo(unsigned u) { return __uint_as_float(u << 16); }
__device__ __forceinline__ float bf_hi(unsigned u) { return __uint_as_float(u & 0xFFFF0000u); }

// ---------------- degree + count + rank in ONE u64 atomic per edge ----------------
__global__ void k_deg(const int* __restrict__ ei, const float* __restrict__ ew,
                      unsigned long long* __restrict__ packed, int* __restrict__ rank) {
  int e = blockIdx.x * 256 + threadIdx.x;          // grid exact: N_EDGES % 256 == 0
  int d = ei[N_EDGES + e];
  u64 fx = (u64)(ew[e] * DEG_SCALE + 0.5f);
  u64 old = atomicAdd(&packed[d], (1ull << DEG_SHIFT) | fx);
  rank[e] = (int)(old >> DEG_SHIFT);               // this edge's slot within its dst bucket
}

// ---------------- merged: scan-partial + dinv/cnt  (blocks 0..NB_SCAN-1)  and W1 repack (32 more)
// W1 frag-major bf16 layout: w1bf[(s*8 + t)*64 + lane] (uint4), n = t*16+(lane&15),
// k = s*32 + (lane>>4)*8 + {0..7}. One B fragment = 1 KB fully contiguous, lane-ordered.
__global__ void k_mid(const unsigned long long* __restrict__ packed,
                      float* __restrict__ dinv, int* __restrict__ cnt, int* __restrict__ bsum,
                      const float* __restrict__ W1, uint4* __restrict__ w1bf,
                      uint2* __restrict__ csr_pad) {
  const int b = blockIdx.x, t = threadIdx.x;
  if (b >= NB_SCAN) {                              // ---- W1 repack part ----
    int idx = (b - NB_SCAN) * 256 + t;             // 0..8191
    if (idx < 8) csr_pad[idx] = make_uint2(0u, 0u);  // safe over-read entries (src=0, w=0)
    int lane = idx & 63;
    int st = idx >> 6;
    int tt = st & 7, ss = st >> 3;
    int n = tt * 16 + (lane & 15);
    int k0 = ss * 32 + (lane >> 4) * 8;
    uint4 v;
    v.x = pack_bf16x2(W1[(size_t)(k0 + 0) * HID + n], W1[(size_t)(k0 + 1) * HID + n]);
    v.y = pack_bf16x2(W1[(size_t)(k0 + 2) * HID + n], W1[(size_t)(k0 + 3) * HID + n]);
    v.z = pack_bf16x2(W1[(size_t)(k0 + 4) * HID + n], W1[(size_t)(k0 + 5) * HID + n]);
    v.w = pack_bf16x2(W1[(size_t)(k0 + 6) * HID + n], W1[(size_t)(k0 + 7) * HID + n]);
    w1bf[idx] = v;
    return;
  }
  // ---- dinv + cnt + per-block partial sum ----
  __shared__ int sh[256];
  int base = b * 1024;
  int v = 0;
#pragma unroll
  for (int q = 0; q < 4; q++) {
    int idx = base + t * 4 + q;
    if (idx < N_NODES) {
      unsigned long long p = packed[idx];
      int c = (int)(p >> DEG_SHIFT);
      cnt[idx] = c;
      dinv[idx] = rsqrtf((float)(p & DEG_WMASK) * DEG_INV_SCALE + 1.0f);  // +1 = self-loop
      v += c;
    }
  }
  sh[t] = v;
  __syncthreads();
  for (int o = 128; o > 0; o >>= 1) {
    if (t < o) sh[t] += sh[t + o];
    __syncthreads();
  }
  if (t == 0) bsum[b] = sh[0];
}

// ---------------- scan-final with FOLDED bsum prefix (serial k_scan_bsum eliminated) -----------
__global__ void k_scan_final(const int* __restrict__ cnt, const int* __restrict__ bsum,
                             int* __restrict__ offs) {
  __shared__ int s[256];
  int t = threadIdx.x;
  // block offset = sum of bsum[j] for j < blockIdx.x
  int c = (t < NB_SCAN && t < blockIdx.x) ? bsum[t] : 0;
  s[t] = c;
  __syncthreads();
  for (int o = 128; o > 0; o >>= 1) {
    if (t < o) s[t] += s[t + o];
    __syncthreads();
  }
  int block_off = s[0];
  __syncthreads();
  // per-block exclusive scan of cnt (4 elems/thread)
  int base = blockIdx.x * 1024;
  int v[4]; int sum = 0;
#pragma unroll
  for (int q = 0; q < 4; q++) {
    int idx = base + t * 4 + q;
    v[q] = (idx < N_NODES) ? cnt[idx] : 0;
    sum += v[q];
  }
  s[t] = sum;
  __syncthreads();
  for (int o = 1; o < 256; o <<= 1) {
    int x = (t >= o) ? s[t - o] : 0;
    __syncthreads();
    s[t] += x;
    __syncthreads();
  }
  int acc = s[t] - sum + block_off;
#pragma unroll
  for (int q = 0; q < 4; q++) {
    int idx = base + t * 4 + q;
    if (idx < N_NODES) offs[idx] = acc;
    acc += v[q];
  }
}

// ---------------- MERGED fill + GEMM1 in one dispatch (independent, complementary pipes) -------
// Every 5th block (bx%5==0, 1563) is a GEMM block; the other 6250 are fill blocks.
//
// GEMM1 v2: K staged in QUARTERS (128 k) instead of halves: slab 33->17 KB per block,
// lifting the LDS occupancy cap 4->8 blocks/CU (VGPR allows 7 waves/SIMD). Round-4 PMC
// showed 25% occupancy / 20% HBM / 4% MFMA = latency-bound; 3.5x more resident waves
// raises loads-in-flight toward the Little's-law requirement. Same per-wave totals:
// 32 float4 global loads, 32 ds_writes, 16 b128 ds_reads, 128 MFMA.
#define QSTR 68   // dwords per LDS row (64 data + 4 pad); 68%32==4 -> same proven bank pattern
__global__ __launch_bounds__(256) void k_fillgemm(
    const int* __restrict__ ei, const float* __restrict__ ew,
    const int* __restrict__ rank, const int* __restrict__ offs, uint2* __restrict__ csr,
    const float* __restrict__ x, const uint4* __restrict__ w1bf,
    const float* __restrict__ dinv, unsigned short* __restrict__ h_u16) {
  __shared__ unsigned slab[4 * 16 * QSTR];         // 17408 B
  const int bx = blockIdx.x;
  const int tid = threadIdx.x;

  if (bx % 5 != 0) {
    // ---------------- fill role: one 8B scatter per edge, no atomics ----------------
    int fb = bx - bx / 5 - 1;                      // 0..6249, bijective over non-multiples of 5
    int e = fb * 256 + tid;
    int s = ei[e];
    int d = ei[N_EDGES + e];
    int p = offs[d] + rank[e];
    csr[p] = make_uint2((unsigned)s, __float_as_uint(ew[e]));
    return;
  }

  // ---------------- gemm role: wave = 16 rows x 128 cols, K=512 ----------------
  const int gb = bx / 5;                           // 0..1562
  const int lane = tid & 63;
  const int wv = tid >> 6;
  const int gw = gb * 4 + wv;                      // global wave id
  if (gw >= N_NODES / 16) return;
  const int m0 = gw * 16;
  unsigned* ws = slab + wv * 16 * QSTR;            // wave-private slab
  const int l16 = lane & 15, quad = lane >> 4;
  const int l32 = lane & 31, rhalf = lane >> 5;    // stage: 2 rows per load round

  f32x4 acc[8];
#pragma unroll
  for (int t = 0; t < 8; t++) acc[t] = (f32x4){0.f, 0.f, 0.f, 0.f};

#pragma unroll
  for (int q = 0; q < 4; q++) {
    // ---- stage quarter q: 16 rows x 128 k; per round one 1KB load covers 2 rows ----
    float4 v[8];
#pragma unroll
    for (int i = 0; i < 8; i++) {
      int row = 2 * i + rhalf;
      v[i] = *(const float4*)(x + (size_t)(m0 + row) * IN_F + q * 128 + l32 * 4);
    }
#pragma unroll
    for (int i = 0; i < 8; i++) {
      int row = 2 * i + rhalf;
      unsigned lo = pack_bf16x2(v[i].x, v[i].y);
      unsigned hi = pack_bf16x2(v[i].z, v[i].w);
      *(uint2*)&ws[row * QSTR + l32 * 2] = make_uint2(lo, hi);
    }
    __threadfence_block();   // wave-local: drain own ds_writes before frag reads
    // ---- compute: 4 k-steps, A frag from LDS, B frags contiguous from global ----
#pragma unroll
    for (int ks = 0; ks < 4; ks++) {
      short8 af = *(const short8*)&ws[l16 * QSTR + ks * 16 + quad * 4];
      const uint4* bbase = w1bf + (size_t)(q * 4 + ks) * 8 * 64 + lane;
#pragma unroll
      for (int t = 0; t < 8; t++) {
        uint4 bv = bbase[t * 64];
        acc[t] = __builtin_amdgcn_mfma_f32_16x16x32_bf16(af, *(const short8*)&bv,
                                                         acc[t], 0, 0, 0);
      }
    }
  }
  // ---- epilogue: C/D row = quad*4+r, col = t*16+l16; scale by dinv[row], store bf16 ----
  float df[4];
#pragma unroll
  for (int r = 0; r < 4; r++) df[r] = dinv[m0 + quad * 4 + r];
#pragma unroll
  for (int t = 0; t < 8; t++)
#pragma unroll
    for (int r = 0; r < 4; r++)
      h_u16[(size_t)(m0 + quad * 4 + r) * HID + t * 16 + l16] = f32_to_bf16(acc[t][r] * df[r]);
}

// ---------------- layer-1 aggregation + ELU + FUSED GEMM2 (act1 never materialized) -------------
// Wave per node. Lane covers feats [2l, 2l+1]. After ELU, 7 per-lane partials vs register W2,
// 6-step butterfly, lanes 0..7 store the 32 B h2 row (pre-scaled by dinv[i], pad col = 0).
__global__ __launch_bounds__(256) void k_agg1(const unsigned* __restrict__ h_u,
    const float* __restrict__ dinv, const int* __restrict__ offs, const int* __restrict__ cnt,
    const uint2* __restrict__ csr, const float* __restrict__ b1,
    const float* __restrict__ W2, float* __restrict__ h2) {
  int i = blockIdx.x * 4 + (threadIdx.x >> 6);   // wave -> node
  int lane = threadIdx.x & 63;                   // lane covers feats [2l, 2l+1]
  if (i >= N_NODES) return;
  float w2a[NCLS], w2b[NCLS];                    // 14 floats, L1-resident after warm-up
#pragma unroll
  for (int c = 0; c < NCLS; c++) {
    w2a[c] = W2[(size_t)(2 * lane) * NCLS + c];
    w2b[c] = W2[(size_t)(2 * lane + 1) * NCLS + c];
  }
  int start = offs[i], len = cnt[i];
  int end = start + len;
  float ax = 0.f, ay = 0.f;
  for (int p = start; p < end; p += 8) {
    uint2 e[8];
#pragma unroll
    for (int k = 0; k < 8; k++) e[k] = csr[p + k];   // padded: safe over-read
    unsigned u[8];
#pragma unroll
    for (int k = 0; k < 8; k++) u[k] = h_u[(size_t)e[k].x * 64 + lane];
#pragma unroll
    for (int k = 0; k < 8; k++) {
      float n = (k == 0 || p + k < end) ? __uint_as_float(e[k].y) : 0.f;
      ax = fmaf(bf_lo(u[k]), n, ax);
      ay = fmaf(bf_hi(u[k]), n, ay);
    }
  }
  float di = dinv[i];
  unsigned u = h_u[(size_t)i * 64 + lane];         // self (already * dinv[i])
  float2 bb = *(const float2*)(b1 + lane * 2);
  float vx = fmaf(di, ax + bf_lo(u), bb.x);
  float vy = fmaf(di, ay + bf_hi(u), bb.y);
  vx = vx > 0.f ? vx : expm1f(vx);                 // ELU (alpha=1)
  vy = vy > 0.f ? vy : expm1f(vy);
  // fused GEMM2: h2[i,:] = dinv[i] * (act1[i,:] @ W2)
  float s[NCLS];
#pragma unroll
  for (int c = 0; c < NCLS; c++) s[c] = fmaf(vy, w2b[c], vx * w2a[c]);
#pragma unroll
  for (int m = 1; m < 64; m <<= 1) {
#pragma unroll
    for (int c = 0; c < NCLS; c++) s[c] += __shfl_xor(s[c], m);
  }
  if (lane < 8) {
    float v = lane == 0 ? s[0] : lane == 1 ? s[1] : lane == 2 ? s[2] :
              lane == 3 ? s[3] : lane == 4 ? s[4] : lane == 5 ? s[5] : s[6];
    h2[(size_t)i * 8 + lane] = (lane < NCLS) ? v * di : 0.f;   // pad col = 0
  }
}

// ---------------- layer-2 aggregation + bias + log_softmax (r0-proven 8-lane/node) ----------------
__global__ __launch_bounds__(256) void k_agg2(const float* __restrict__ h2,
    const float* __restrict__ dinv, const int* __restrict__ offs, const int* __restrict__ cnt,
    const uint2* __restrict__ csr, const float* __restrict__ b2, float* __restrict__ out) {
  int tid = threadIdx.x;
  int i = blockIdx.x * 32 + (tid >> 3);   // 8 lanes per node
  int f = tid & 7;                        // f==7 is padding lane
  if (i >= N_NODES) return;
  int start = offs[i], len = cnt[i];
  int end = start + len;
  float acc = 0.0f;
  for (int p = start; p < end; p += 4) {
    uint2 e0 = csr[p];
    uint2 e1 = csr[p + 1];
    uint2 e2 = csr[p + 2];
    uint2 e3 = csr[p + 3];
    float v0 = h2[(size_t)e0.x * 8 + f];
    float v1 = h2[(size_t)e1.x * 8 + f];
    float v2 = h2[(size_t)e2.x * 8 + f];
    float v3 = h2[(size_t)e3.x * 8 + f];
    float n0 = __uint_as_float(e0.y);
    float n1 = (p + 1 < end) ? __uint_as_float(e1.y) : 0.f;
    float n2 = (p + 2 < end) ? __uint_as_float(e2.y) : 0.f;
    float n3 = (p + 3 < end) ? __uint_as_float(e3.y) : 0.f;
    acc = fmaf(v0, n0, acc);
    acc = fmaf(v1, n1, acc);
    acc = fmaf(v2, n2, acc);
    acc = fmaf(v3, n3, acc);
  }
  float di = dinv[i];
  float v = fmaf(di, acc + h2[(size_t)i * 8 + f], (f < NCLS) ? b2[f] : 0.0f);
  float vm = (f < NCLS) ? v : -INFINITY;
#pragma unroll
  for (int o = 1; o < 8; o <<= 1) vm = fmaxf(vm, __shfl_xor(vm, o, 8));
  float ex = (f < NCLS) ? expf(v - vm) : 0.0f;
  float s8 = ex;
#pragma unroll
  for (int o = 1; o < 8; o <<= 1) s8 += __shfl_xor(s8, o, 8);
  float lse = logf(s8);
  if (f < NCLS) out[(size_t)i * NCLS + f] = v - vm - lse;
}

// ---------------- launch ----------------
extern "C" void kernel_launch(void* const* d_in, const int* in_sizes, int n_in,
                              void* d_out, int out_size, void* d_ws, size_t ws_size,
                              hipStream_t stream) {
  const float* x  = (const float*)d_in[0];
  const int*   ei = (const int*)d_in[1];
  const float* ew = (const float*)d_in[2];
  const float* W1 = (const float*)d_in[3];
  const float* b1 = (const float*)d_in[4];
  const float* W2 = (const float*)d_in[5];
  const float* b2 = (const float*)d_in[6];
  float* out = (float*)d_out;

  char* w = (char*)d_ws;
  const size_t Npad  = ((size_t)N_NODES * 4 + 255) & ~(size_t)255;
  const size_t Npad8 = ((size_t)N_NODES * 8 + 255) & ~(size_t)255;
  const size_t Epad  = ((size_t)N_EDGES * 4 + 255) & ~(size_t)255;
  size_t off = 0;
  unsigned long long* packed = (unsigned long long*)(w + off); off += Npad8;  // zeroed
  float*    dinv     = (float*)(w + off);    off += Npad;
  int*      cnt      = (int*)(w + off);      off += Npad;
  int*      offs     = (int*)(w + off);      off += Npad;
  int*      bsum     = (int*)(w + off);      off += 1024;
  int*      rank     = (int*)(w + off);      off += Epad;
  uint2*    csr      = (uint2*)(w + off);    off += ((size_t)(N_EDGES + 8) * 8 + 255) & ~(size_t)255;
  uint4*    w1bf     = (uint4*)(w + off);    off += (size_t)8192 * 16;        // 128 KB
  unsigned short* h_u16 = (unsigned short*)(w + off); off += (size_t)N_NODES * HID * 2;
  float*    h2       = (float*)(w + off);    off += (size_t)N_NODES * 8 * 4;

  hipMemsetAsync(packed, 0, Npad8, stream);

  k_deg<<<N_EDGES / 256, 256, 0, stream>>>(ei, ew, packed, rank);
  k_mid<<<NB_SCAN + 32, 256, 0, stream>>>(packed, dinv, cnt, bsum, W1, w1bf, csr + N_EDGES);
  k_scan_final<<<NB_SCAN, 256, 0, stream>>>(cnt, bsum, offs);
  k_fillgemm<<<G_MERGED, 256, 0, stream>>>(ei, ew, rank, offs, csr, x, w1bf, dinv, h_u16);
  k_agg1<<<(N_NODES + 3) / 4, 256, 0, stream>>>((const unsigned*)h_u16, dinv, offs, cnt,
                                                csr, b1, W2, h2);
  k_agg2<<<N_NODES / 32, 256, 0, stream>>>(h2, dinv, offs, cnt, csr, b2, out);
}

// Round 7
// 494.833 us; speedup vs baseline: 1.0614x; 1.0614x over previous
//
#include <hip/hip_runtime.h>
#include <math.h>

#define N_NODES 100000
#define N_EDGES 1600000
#define IN_F 512
#define HID 128
#define NCLS 7

#define DEG_SHIFT 43
#define DEG_WMASK ((1ull << 43) - 1)
#define DEG_SCALE 4194304.0f          // 2^22
#define DEG_INV_SCALE (1.0f / 4194304.0f)
#define NB_SCAN 98                    // ceil(100000 / 1024)

// merged fill+gemm grid (512-thread blocks)
#define FILL_BLOCKS 3125              // N_EDGES / 512
#define GEMM_BLOCKS 782               // ceil(6250 waves / 8)
#define G2 (FILL_BLOCKS + GEMM_BLOCKS)  // 3907; bx%5==0 -> gemm (782), else fill (3125)

typedef short short8 __attribute__((ext_vector_type(8)));
typedef float f32x4 __attribute__((ext_vector_type(4)));
typedef unsigned long long u64;

__device__ __forceinline__ unsigned pack_bf16x2(float a, float b) {
  unsigned ua = __float_as_uint(a), ub = __float_as_uint(b);
  unsigned ra = (ua + 0x7FFFu + ((ua >> 16) & 1u)) >> 16;     // RNE
  unsigned rb = (ub + 0x7FFFu + ((ub >> 16) & 1u)) >> 16;
  return ra | (rb << 16);
}
__device__ __forceinline__ unsigned short f32_to_bf16(float v) {
  unsigned u = __float_as_uint(v);
  return (unsigned short)((u + 0x7FFFu + ((u >> 16) & 1u)) >> 16);
}
__device__ __forceinline__ float bf_lo(unsigned u) { return __uint_as_float(u << 16); }
__device__ __forceinline__ float bf_hi(unsigned u) { return __uint_as_float(u & 0xFFFF0000u); }

// ---------------- degree + count + rank in ONE u64 atomic per edge ----------------
__global__ void k_deg(const int* __restrict__ ei, const float* __restrict__ ew,
                      unsigned long long* __restrict__ packed, int* __restrict__ rank) {
  int e = blockIdx.x * 256 + threadIdx.x;          // grid exact: N_EDGES % 256 == 0
  int d = ei[N_EDGES + e];
  u64 fx = (u64)(ew[e] * DEG_SCALE + 0.5f);
  u64 old = atomicAdd(&packed[d], (1ull << DEG_SHIFT) | fx);
  rank[e] = (int)(old >> DEG_SHIFT);               // this edge's slot within its dst bucket
}

// ---------------- merged: scan-partial + dinv/cnt  (blocks 0..NB_SCAN-1)  and W1 repack (32 more)
// W1 frag-major bf16 layout: w1bf[(s*8 + t)*64 + lane] (uint4), n = t*16+(lane&15),
// k = s*32 + (lane>>4)*8 + {0..7}. One B fragment = 1 KB fully contiguous, lane-ordered.
__global__ void k_mid(const unsigned long long* __restrict__ packed,
                      float* __restrict__ dinv, int* __restrict__ cnt, int* __restrict__ bsum,
                      const float* __restrict__ W1, uint4* __restrict__ w1bf,
                      uint2* __restrict__ csr_pad) {
  const int b = blockIdx.x, t = threadIdx.x;
  if (b >= NB_SCAN) {                              // ---- W1 repack part ----
    int idx = (b - NB_SCAN) * 256 + t;             // 0..8191
    if (idx < 8) csr_pad[idx] = make_uint2(0u, 0u);  // safe over-read entries (src=0, w=0)
    int lane = idx & 63;
    int st = idx >> 6;
    int tt = st & 7, ss = st >> 3;
    int n = tt * 16 + (lane & 15);
    int k0 = ss * 32 + (lane >> 4) * 8;
    uint4 v;
    v.x = pack_bf16x2(W1[(size_t)(k0 + 0) * HID + n], W1[(size_t)(k0 + 1) * HID + n]);
    v.y = pack_bf16x2(W1[(size_t)(k0 + 2) * HID + n], W1[(size_t)(k0 + 3) * HID + n]);
    v.z = pack_bf16x2(W1[(size_t)(k0 + 4) * HID + n], W1[(size_t)(k0 + 5) * HID + n]);
    v.w = pack_bf16x2(W1[(size_t)(k0 + 6) * HID + n], W1[(size_t)(k0 + 7) * HID + n]);
    w1bf[idx] = v;
    return;
  }
  // ---- dinv + cnt + per-block partial sum ----
  __shared__ int sh[256];
  int base = b * 1024;
  int v = 0;
#pragma unroll
  for (int q = 0; q < 4; q++) {
    int idx = base + t * 4 + q;
    if (idx < N_NODES) {
      unsigned long long p = packed[idx];
      int c = (int)(p >> DEG_SHIFT);
      cnt[idx] = c;
      dinv[idx] = rsqrtf((float)(p & DEG_WMASK) * DEG_INV_SCALE + 1.0f);  // +1 = self-loop
      v += c;
    }
  }
  sh[t] = v;
  __syncthreads();
  for (int o = 128; o > 0; o >>= 1) {
    if (t < o) sh[t] += sh[t + o];
    __syncthreads();
  }
  if (t == 0) bsum[b] = sh[0];
}

// ---------------- scan-final with FOLDED bsum prefix (serial k_scan_bsum eliminated) -----------
__global__ void k_scan_final(const int* __restrict__ cnt, const int* __restrict__ bsum,
                             int* __restrict__ offs) {
  __shared__ int s[256];
  int t = threadIdx.x;
  // block offset = sum of bsum[j] for j < blockIdx.x
  int c = (t < NB_SCAN && t < blockIdx.x) ? bsum[t] : 0;
  s[t] = c;
  __syncthreads();
  for (int o = 128; o > 0; o >>= 1) {
    if (t < o) s[t] += s[t + o];
    __syncthreads();
  }
  int block_off = s[0];
  __syncthreads();
  // per-block exclusive scan of cnt (4 elems/thread)
  int base = blockIdx.x * 1024;
  int v[4]; int sum = 0;
#pragma unroll
  for (int q = 0; q < 4; q++) {
    int idx = base + t * 4 + q;
    v[q] = (idx < N_NODES) ? cnt[idx] : 0;
    sum += v[q];
  }
  s[t] = sum;
  __syncthreads();
  for (int o = 1; o < 256; o <<= 1) {
    int x = (t >= o) ? s[t - o] : 0;
    __syncthreads();
    s[t] += x;
    __syncthreads();
  }
  int acc = s[t] - sum + block_off;
#pragma unroll
  for (int q = 0; q < 4; q++) {
    int idx = base + t * 4 + q;
    if (idx < N_NODES) offs[idx] = acc;
    acc += v[q];
  }
}

// ---------------- MERGED fill + GEMM1, v3: B staged in LDS once per block ----------------
// Round-6 PMC (MfmaUtil 3.7, VALUBusy 6, HBM 18%, occ 31%): waves stall on B-fragment reads.
// Old scheme: every wave re-read all 128 KB of w1bf from L2/L3 -> 800 MB of B traffic, served
// from L3 because the 204.8 MB x-stream thrashes the 4 MB/XCD L2.  New scheme: 512-thread
// blocks (8 waves x 16 rows = M=128/block); per K-quarter the block stages the 32 KB B-quarter
// into LDS (total B traffic 782*128KB = 100 MB, 8x cut) and waves read fragments with
// contiguous conflict-free ds_read_b128.  A goes direct global->register (round-1-proven
// fragment pattern: per k-step, lane(l16,quad) reads A[l16][q*128+ks*32+quad*8..+7], union =
// 16 rows x 128 B fully dense).  LDS 32 KB/block -> 3-4 blocks/CU co-resident.
__global__ __launch_bounds__(512) void k_fillgemm(
    const int* __restrict__ ei, const float* __restrict__ ew,
    const int* __restrict__ rank, const int* __restrict__ offs, uint2* __restrict__ csr,
    const float* __restrict__ x, const uint4* __restrict__ w1bf,
    const float* __restrict__ dinv, unsigned short* __restrict__ h_u16) {
  __shared__ uint4 lds_b[2048];                    // one K-quarter of B: 32 KB
  const int bx = blockIdx.x;
  const int tid = threadIdx.x;

  if (bx % 5 != 0) {
    // ---------------- fill role: one 8B scatter per edge, no atomics ----------------
    int fb = bx - bx / 5 - 1;                      // 0..3124, bijective over non-multiples of 5
    int e = fb * 512 + tid;
    int s = ei[e];
    int d = ei[N_EDGES + e];
    int p = offs[d] + rank[e];
    csr[p] = make_uint2((unsigned)s, __float_as_uint(ew[e]));
    return;
  }

  // ---------------- gemm role: block = 8 waves x 16 rows, N=128, K=512 ----------------
  const int gb = bx / 5;                           // 0..781
  const int lane = tid & 63;
  const int wv = tid >> 6;
  const int gw = gb * 8 + wv;                      // global wave id, 0..6255
  const int m0 = gw * 16;
  const bool act = (m0 < N_NODES);                 // 6250 waves active (last block: 2 of 8)
  const int l16 = lane & 15, quad = lane >> 4;
  const float* arow = x + (size_t)(m0 + l16) * IN_F + quad * 8;

  f32x4 acc[8];
#pragma unroll
  for (int t = 0; t < 8; t++) acc[t] = (f32x4){0.f, 0.f, 0.f, 0.f};

  for (int q = 0; q < 4; q++) {
    // A-loads for this quarter issued FIRST: HBM latency hides under B staging + barrier
    float4 v[8];
    if (act) {
#pragma unroll
      for (int ks = 0; ks < 4; ks++) {
        const float* ap = arow + q * 128 + ks * 32;
        v[2 * ks]     = *(const float4*)ap;
        v[2 * ks + 1] = *(const float4*)(ap + 4);
      }
    }
    if (q > 0) __syncthreads();                    // prior quarter's readers done before overwrite
    // stage B quarter q: 2048 uint4, fully coalesced, 4 per thread
#pragma unroll
    for (int j = 0; j < 4; j++)
      lds_b[tid + j * 512] = w1bf[q * 2048 + tid + j * 512];
    __syncthreads();
    if (act) {
#pragma unroll
      for (int ks = 0; ks < 4; ks++) {
        uint4 au;
        au.x = pack_bf16x2(v[2 * ks].x, v[2 * ks].y);
        au.y = pack_bf16x2(v[2 * ks].z, v[2 * ks].w);
        au.z = pack_bf16x2(v[2 * ks + 1].x, v[2 * ks + 1].y);
        au.w = pack_bf16x2(v[2 * ks + 1].z, v[2 * ks + 1].w);
        short8 af = *(short8*)&au;
        const uint4* bbase = lds_b + ks * 512 + lane;   // frag = 1 KB contiguous in LDS
#pragma unroll
        for (int t = 0; t < 8; t++) {
          uint4 bv = bbase[t * 64];
          acc[t] = __builtin_amdgcn_mfma_f32_16x16x32_bf16(af, *(const short8*)&bv,
                                                           acc[t], 0, 0, 0);
        }
      }
    }
  }
  // ---- epilogue: C/D row = quad*4+r, col = t*16+l16; scale by dinv[row], store bf16 ----
  if (act) {
    float df[4];
#pragma unroll
    for (int r = 0; r < 4; r++) df[r] = dinv[m0 + quad * 4 + r];
#pragma unroll
    for (int t = 0; t < 8; t++)
#pragma unroll
      for (int r = 0; r < 4; r++)
        h_u16[(size_t)(m0 + quad * 4 + r) * HID + t * 16 + l16] = f32_to_bf16(acc[t][r] * df[r]);
  }
}

// ---------------- layer-1 aggregation + ELU + FUSED GEMM2 (act1 never materialized) -------------
// Wave per node. Lane covers feats [2l, 2l+1]. After ELU, 7 per-lane partials vs register W2,
// 6-step butterfly, lanes 0..7 store the 32 B h2 row (pre-scaled by dinv[i], pad col = 0).
__global__ __launch_bounds__(256) void k_agg1(const unsigned* __restrict__ h_u,
    const float* __restrict__ dinv, const int* __restrict__ offs, const int* __restrict__ cnt,
    const uint2* __restrict__ csr, const float* __restrict__ b1,
    const float* __restrict__ W2, float* __restrict__ h2) {
  int i = blockIdx.x * 4 + (threadIdx.x >> 6);   // wave -> node
  int lane = threadIdx.x & 63;                   // lane covers feats [2l, 2l+1]
  if (i >= N_NODES) return;
  float w2a[NCLS], w2b[NCLS];                    // 14 floats, L1-resident after warm-up
#pragma unroll
  for (int c = 0; c < NCLS; c++) {
    w2a[c] = W2[(size_t)(2 * lane) * NCLS + c];
    w2b[c] = W2[(size_t)(2 * lane + 1) * NCLS + c];
  }
  int start = offs[i], len = cnt[i];
  int end = start + len;
  float ax = 0.f, ay = 0.f;
  for (int p = start; p < end; p += 8) {
    uint2 e[8];
#pragma unroll
    for (int k = 0; k < 8; k++) e[k] = csr[p + k];   // padded: safe over-read
    unsigned u[8];
#pragma unroll
    for (int k = 0; k < 8; k++) u[k] = h_u[(size_t)e[k].x * 64 + lane];
#pragma unroll
    for (int k = 0; k < 8; k++) {
      float n = (k == 0 || p + k < end) ? __uint_as_float(e[k].y) : 0.f;
      ax = fmaf(bf_lo(u[k]), n, ax);
      ay = fmaf(bf_hi(u[k]), n, ay);
    }
  }
  float di = dinv[i];
  unsigned u = h_u[(size_t)i * 64 + lane];         // self (already * dinv[i])
  float2 bb = *(const float2*)(b1 + lane * 2);
  float vx = fmaf(di, ax + bf_lo(u), bb.x);
  float vy = fmaf(di, ay + bf_hi(u), bb.y);
  vx = vx > 0.f ? vx : expm1f(vx);                 // ELU (alpha=1)
  vy = vy > 0.f ? vy : expm1f(vy);
  // fused GEMM2: h2[i,:] = dinv[i] * (act1[i,:] @ W2)
  float s[NCLS];
#pragma unroll
  for (int c = 0; c < NCLS; c++) s[c] = fmaf(vy, w2b[c], vx * w2a[c]);
#pragma unroll
  for (int m = 1; m < 64; m <<= 1) {
#pragma unroll
    for (int c = 0; c < NCLS; c++) s[c] += __shfl_xor(s[c], m);
  }
  if (lane < 8) {
    float v = lane == 0 ? s[0] : lane == 1 ? s[1] : lane == 2 ? s[2] :
              lane == 3 ? s[3] : lane == 4 ? s[4] : lane == 5 ? s[5] : s[6];
    h2[(size_t)i * 8 + lane] = (lane < NCLS) ? v * di : 0.f;   // pad col = 0
  }
}

// ---------------- layer-2 aggregation + bias + log_softmax (r0-proven 8-lane/node) ----------------
__global__ __launch_bounds__(256) void k_agg2(const float* __restrict__ h2,
    const float* __restrict__ dinv, const int* __restrict__ offs, const int* __restrict__ cnt,
    const uint2* __restrict__ csr, const float* __restrict__ b2, float* __restrict__ out) {
  int tid = threadIdx.x;
  int i = blockIdx.x * 32 + (tid >> 3);   // 8 lanes per node
  int f = tid & 7;                        // f==7 is padding lane
  if (i >= N_NODES) return;
  int start = offs[i], len = cnt[i];
  int end = start + len;
  float acc = 0.0f;
  for (int p = start; p < end; p += 4) {
    uint2 e0 = csr[p];
    uint2 e1 = csr[p + 1];
    uint2 e2 = csr[p + 2];
    uint2 e3 = csr[p + 3];
    float v0 = h2[(size_t)e0.x * 8 + f];
    float v1 = h2[(size_t)e1.x * 8 + f];
    float v2 = h2[(size_t)e2.x * 8 + f];
    float v3 = h2[(size_t)e3.x * 8 + f];
    float n0 = __uint_as_float(e0.y);
    float n1 = (p + 1 < end) ? __uint_as_float(e1.y) : 0.f;
    float n2 = (p + 2 < end) ? __uint_as_float(e2.y) : 0.f;
    float n3 = (p + 3 < end) ? __uint_as_float(e3.y) : 0.f;
    acc = fmaf(v0, n0, acc);
    acc = fmaf(v1, n1, acc);
    acc = fmaf(v2, n2, acc);
    acc = fmaf(v3, n3, acc);
  }
  float di = dinv[i];
  float v = fmaf(di, acc + h2[(size_t)i * 8 + f], (f < NCLS) ? b2[f] : 0.0f);
  float vm = (f < NCLS) ? v : -INFINITY;
#pragma unroll
  for (int o = 1; o < 8; o <<= 1) vm = fmaxf(vm, __shfl_xor(vm, o, 8));
  float ex = (f < NCLS) ? expf(v - vm) : 0.0f;
  float s8 = ex;
#pragma unroll
  for (int o = 1; o < 8; o <<= 1) s8 += __shfl_xor(s8, o, 8);
  float lse = logf(s8);
  if (f < NCLS) out[(size_t)i * NCLS + f] = v - vm - lse;
}

// ---------------- launch ----------------
extern "C" void kernel_launch(void* const* d_in, const int* in_sizes, int n_in,
                              void* d_out, int out_size, void* d_ws, size_t ws_size,
                              hipStream_t stream) {
  const float* x  = (const float*)d_in[0];
  const int*   ei = (const int*)d_in[1];
  const float* ew = (const float*)d_in[2];
  const float* W1 = (const float*)d_in[3];
  const float* b1 = (const float*)d_in[4];
  const float* W2 = (const float*)d_in[5];
  const float* b2 = (const float*)d_in[6];
  float* out = (float*)d_out;

  char* w = (char*)d_ws;
  const size_t Npad  = ((size_t)N_NODES * 4 + 255) & ~(size_t)255;
  const size_t Npad8 = ((size_t)N_NODES * 8 + 255) & ~(size_t)255;
  const size_t Epad  = ((size_t)N_EDGES * 4 + 255) & ~(size_t)255;
  size_t off = 0;
  unsigned long long* packed = (unsigned long long*)(w + off); off += Npad8;  // zeroed
  float*    dinv     = (float*)(w + off);    off += Npad;
  int*      cnt      = (int*)(w + off);      off += Npad;
  int*      offs     = (int*)(w + off);      off += Npad;
  int*      bsum     = (int*)(w + off);      off += 1024;
  int*      rank     = (int*)(w + off);      off += Epad;
  uint2*    csr      = (uint2*)(w + off);    off += ((size_t)(N_EDGES + 8) * 8 + 255) & ~(size_t)255;
  uint4*    w1bf     = (uint4*)(w + off);    off += (size_t)8192 * 16;        // 128 KB
  unsigned short* h_u16 = (unsigned short*)(w + off); off += (size_t)N_NODES * HID * 2;
  float*    h2       = (float*)(w + off);    off += (size_t)N_NODES * 8 * 4;

  hipMemsetAsync(packed, 0, Npad8, stream);

  k_deg<<<N_EDGES / 256, 256, 0, stream>>>(ei, ew, packed, rank);
  k_mid<<<NB_SCAN + 32, 256, 0, stream>>>(packed, dinv, cnt, bsum, W1, w1bf, csr + N_EDGES);
  k_scan_final<<<NB_SCAN, 256, 0, stream>>>(cnt, bsum, offs);
  k_fillgemm<<<G2, 512, 0, stream>>>(ei, ew, rank, offs, csr, x, w1bf, dinv, h_u16);
  k_agg1<<<(N_NODES + 3) / 4, 256, 0, stream>>>((const unsigned*)h_u16, dinv, offs, cnt,
                                                csr, b1, W2, h2);
  k_agg2<<<N_NODES / 32, 256, 0, stream>>>(h2, dinv, offs, cnt, csr, b2, out);
}

// Round 8
// 482.943 us; speedup vs baseline: 1.0875x; 1.0246x over previous
//
#include <hip/hip_runtime.h>
#include <math.h>

#define N_NODES 100000
#define N_EDGES 1600000
#define IN_F 512
#define HID 128
#define NCLS 7

#define DEG_SHIFT 43
#define DEG_WMASK ((1ull << 43) - 1)
#define DEG_SCALE 4194304.0f          // 2^22
#define DEG_INV_SCALE (1.0f / 4194304.0f)
#define NB_SCAN 98                    // ceil(100000 / 1024)

// merged deg+conv grid: 6250 deg blocks (bx%5==0) + 25000 conversion blocks
#define G_DEGCONV 31250
// merged fill+gemm grid (512-thread blocks)
#define FILL_BLOCKS 3125              // N_EDGES / 512
#define GEMM_BLOCKS 782               // ceil(6250 waves / 8)
#define G2 (FILL_BLOCKS + GEMM_BLOCKS)  // 3907; bx%5==0 -> gemm (782), else fill (3125)

typedef short short8 __attribute__((ext_vector_type(8)));
typedef float f32x4 __attribute__((ext_vector_type(4)));
typedef unsigned long long u64;

__device__ __forceinline__ unsigned pack_bf16x2(float a, float b) {
  unsigned ua = __float_as_uint(a), ub = __float_as_uint(b);
  unsigned ra = (ua + 0x7FFFu + ((ua >> 16) & 1u)) >> 16;     // RNE
  unsigned rb = (ub + 0x7FFFu + ((ub >> 16) & 1u)) >> 16;
  return ra | (rb << 16);
}
__device__ __forceinline__ unsigned short f32_to_bf16(float v) {
  unsigned u = __float_as_uint(v);
  return (unsigned short)((u + 0x7FFFu + ((u >> 16) & 1u)) >> 16);
}
__device__ __forceinline__ float bf_lo(unsigned u) { return __uint_as_float(u << 16); }
__device__ __forceinline__ float bf_hi(unsigned u) { return __uint_as_float(u & 0xFFFF0000u); }

// ---------------- MERGED: degree/rank atomics + x -> bf16 fragment-major conversion ----------
// deg role (bx%5==0): one u64 atomic per edge (count | fixed-point wsum), rank from return.
// conv role (else): xbf[((gw*16 + ks2)*64 + lane)] (uint4) = bf16 A-fragment for wave gw,
// k-step ks2, lane: rows gw*16+(lane&15), k = ks2*32+(lane>>4)*8 + {0..7}.  The gemm then
// loads each lane's fragment as ONE contiguous 16 B uint4 (per wave: 1 KB dense per k-step),
// no strided pieces, no VALU pack.  Conversion rides k_deg's idle BW (deg is atomic-bound).
__global__ void k_degconv(const int* __restrict__ ei, const float* __restrict__ ew,
                          unsigned long long* __restrict__ packed, int* __restrict__ rank,
                          const float* __restrict__ x, uint4* __restrict__ xbf) {
  const int bx = blockIdx.x, tid = threadIdx.x;
  if (bx % 5 == 0) {
    int e = (bx / 5) * 256 + tid;                  // bx/5 in 0..6249 -> all 1.6M edges
    int d = ei[N_EDGES + e];
    u64 fx = (u64)(ew[e] * DEG_SCALE + 0.5f);
    u64 old = atomicAdd(&packed[d], (1ull << DEG_SHIFT) | fx);
    rank[e] = (int)(old >> DEG_SHIFT);             // this edge's slot within its dst bucket
    return;
  }
  int cb = bx - bx / 5 - 1;                        // 0..24999, bijective over non-mult-of-5
  int chunk = cb * 256 + tid;                      // 0..6,399,999
  int gw = chunk >> 10;                            // 1024 chunks per 16-row wave tile
  int rem = chunk & 1023;
  int ks2 = rem >> 6;
  int lane = rem & 63;
  int m = gw * 16 + (lane & 15);
  int kbase = ks2 * 32 + (lane >> 4) * 8;
  const float* ap = x + (size_t)m * IN_F + kbase;  // 32B-aligned (kbase % 8 == 0)
  float4 a0 = *(const float4*)ap;
  float4 a1 = *(const float4*)(ap + 4);
  uint4 v;
  v.x = pack_bf16x2(a0.x, a0.y);
  v.y = pack_bf16x2(a0.z, a0.w);
  v.z = pack_bf16x2(a1.x, a1.y);
  v.w = pack_bf16x2(a1.z, a1.w);
  xbf[chunk] = v;                                  // stores: 1 KB contiguous per wave
}

// ---------------- merged: scan-partial + dinv/cnt  (blocks 0..NB_SCAN-1)  and W1 repack (32 more)
// W1 frag-major bf16 layout: w1bf[(s*8 + t)*64 + lane] (uint4), n = t*16+(lane&15),
// k = s*32 + (lane>>4)*8 + {0..7}. One B fragment = 1 KB fully contiguous, lane-ordered.
__global__ void k_mid(const unsigned long long* __restrict__ packed,
                      float* __restrict__ dinv, int* __restrict__ cnt, int* __restrict__ bsum,
                      const float* __restrict__ W1, uint4* __restrict__ w1bf,
                      uint2* __restrict__ csr_pad) {
  const int b = blockIdx.x, t = threadIdx.x;
  if (b >= NB_SCAN) {                              // ---- W1 repack part ----
    int idx = (b - NB_SCAN) * 256 + t;             // 0..8191
    if (idx < 8) csr_pad[idx] = make_uint2(0u, 0u);  // safe over-read entries (src=0, w=0)
    int lane = idx & 63;
    int st = idx >> 6;
    int tt = st & 7, ss = st >> 3;
    int n = tt * 16 + (lane & 15);
    int k0 = ss * 32 + (lane >> 4) * 8;
    uint4 v;
    v.x = pack_bf16x2(W1[(size_t)(k0 + 0) * HID + n], W1[(size_t)(k0 + 1) * HID + n]);
    v.y = pack_bf16x2(W1[(size_t)(k0 + 2) * HID + n], W1[(size_t)(k0 + 3) * HID + n]);
    v.z = pack_bf16x2(W1[(size_t)(k0 + 4) * HID + n], W1[(size_t)(k0 + 5) * HID + n]);
    v.w = pack_bf16x2(W1[(size_t)(k0 + 6) * HID + n], W1[(size_t)(k0 + 7) * HID + n]);
    w1bf[idx] = v;
    return;
  }
  // ---- dinv + cnt + per-block partial sum ----
  __shared__ int sh[256];
  int base = b * 1024;
  int v = 0;
#pragma unroll
  for (int q = 0; q < 4; q++) {
    int idx = base + t * 4 + q;
    if (idx < N_NODES) {
      unsigned long long p = packed[idx];
      int c = (int)(p >> DEG_SHIFT);
      cnt[idx] = c;
      dinv[idx] = rsqrtf((float)(p & DEG_WMASK) * DEG_INV_SCALE + 1.0f);  // +1 = self-loop
      v += c;
    }
  }
  sh[t] = v;
  __syncthreads();
  for (int o = 128; o > 0; o >>= 1) {
    if (t < o) sh[t] += sh[t + o];
    __syncthreads();
  }
  if (t == 0) bsum[b] = sh[0];
}

// ---------------- scan-final with FOLDED bsum prefix (serial k_scan_bsum eliminated) -----------
__global__ void k_scan_final(const int* __restrict__ cnt, const int* __restrict__ bsum,
                             int* __restrict__ offs) {
  __shared__ int s[256];
  int t = threadIdx.x;
  // block offset = sum of bsum[j] for j < blockIdx.x
  int c = (t < NB_SCAN && t < blockIdx.x) ? bsum[t] : 0;
  s[t] = c;
  __syncthreads();
  for (int o = 128; o > 0; o >>= 1) {
    if (t < o) s[t] += s[t + o];
    __syncthreads();
  }
  int block_off = s[0];
  __syncthreads();
  // per-block exclusive scan of cnt (4 elems/thread)
  int base = blockIdx.x * 1024;
  int v[4]; int sum = 0;
#pragma unroll
  for (int q = 0; q < 4; q++) {
    int idx = base + t * 4 + q;
    v[q] = (idx < N_NODES) ? cnt[idx] : 0;
    sum += v[q];
  }
  s[t] = sum;
  __syncthreads();
  for (int o = 1; o < 256; o <<= 1) {
    int x = (t >= o) ? s[t - o] : 0;
    __syncthreads();
    s[t] += x;
    __syncthreads();
  }
  int acc = s[t] - sum + block_off;
#pragma unroll
  for (int q = 0; q < 4; q++) {
    int idx = base + t * 4 + q;
    if (idx < N_NODES) offs[idx] = acc;
    acc += v[q];
  }
}

// ---------------- MERGED fill + GEMM1, v4: bf16 fragment-major A + B in LDS ----------------
// Round-7 PMC (MfmaUtil 4.1, VALUBusy 7.6, HBM 20%, occ 20%): still latency-bound; A-path
// (strided f32 pieces + VALU pack between load and MFMA) is the critical path.  Now A comes
// from xbf: one contiguous 16 B uint4 per lane per k-step, ALL 16 k-steps issued upfront
// (64 VGPR of A in flight, L3-resident since k_degconv just wrote it).  No packs in the
// MFMA loop at all.  B staged per-quarter in LDS as in v3 (proven +17 us).
__global__ __launch_bounds__(512) void k_fillgemm(
    const int* __restrict__ ei, const float* __restrict__ ew,
    const int* __restrict__ rank, const int* __restrict__ offs, uint2* __restrict__ csr,
    const uint4* __restrict__ xbf, const uint4* __restrict__ w1bf,
    const float* __restrict__ dinv, unsigned short* __restrict__ h_u16) {
  __shared__ uint4 lds_b[2048];                    // one K-quarter of B: 32 KB
  const int bx = blockIdx.x;
  const int tid = threadIdx.x;

  if (bx % 5 != 0) {
    // ---------------- fill role: one 8B scatter per edge, no atomics ----------------
    int fb = bx - bx / 5 - 1;                      // 0..3124, bijective over non-multiples of 5
    int e = fb * 512 + tid;
    int s = ei[e];
    int d = ei[N_EDGES + e];
    int p = offs[d] + rank[e];
    csr[p] = make_uint2((unsigned)s, __float_as_uint(ew[e]));
    return;
  }

  // ---------------- gemm role: block = 8 waves x 16 rows, N=128, K=512 ----------------
  const int gb = bx / 5;                           // 0..781
  const int lane = tid & 63;
  const int wv = tid >> 6;
  const int gw = gb * 8 + wv;                      // global wave id, 0..6255
  const int m0 = gw * 16;
  const bool act = (m0 < N_NODES);                 // 6250 waves active (last block: 2 of 8)
  const int l16 = lane & 15, quad = lane >> 4;

  // issue ALL 16 A-fragment loads upfront: contiguous, each 16 B/lane (1 KB/wave/k-step)
  uint4 a[16];
  if (act) {
    const uint4* ab = xbf + (size_t)gw * 1024 + lane;
#pragma unroll
    for (int i = 0; i < 16; i++) a[i] = ab[i * 64];
  }

  f32x4 acc[8];
#pragma unroll
  for (int t = 0; t < 8; t++) acc[t] = (f32x4){0.f, 0.f, 0.f, 0.f};

  for (int q = 0; q < 4; q++) {
    if (q > 0) __syncthreads();                    // prior quarter's readers done before overwrite
    // stage B quarter q: 2048 uint4, fully coalesced, 4 per thread (L2-resident 128 KB)
#pragma unroll
    for (int j = 0; j < 4; j++)
      lds_b[tid + j * 512] = w1bf[q * 2048 + tid + j * 512];
    __syncthreads();
    if (act) {
#pragma unroll
      for (int ks = 0; ks < 4; ks++) {
        short8 af = *(const short8*)&a[q * 4 + ks];
        const uint4* bbase = lds_b + ks * 512 + lane;   // frag = 1 KB contiguous in LDS
#pragma unroll
        for (int t = 0; t < 8; t++) {
          uint4 bv = bbase[t * 64];
          acc[t] = __builtin_amdgcn_mfma_f32_16x16x32_bf16(af, *(const short8*)&bv,
                                                           acc[t], 0, 0, 0);
        }
      }
    }
  }
  // ---- epilogue: C/D row = quad*4+r, col = t*16+l16; scale by dinv[row], store bf16 ----
  if (act) {
    float df[4];
#pragma unroll
    for (int r = 0; r < 4; r++) df[r] = dinv[m0 + quad * 4 + r];
#pragma unroll
    for (int t = 0; t < 8; t++)
#pragma unroll
      for (int r = 0; r < 4; r++)
        h_u16[(size_t)(m0 + quad * 4 + r) * HID + t * 16 + l16] = f32_to_bf16(acc[t][r] * df[r]);
  }
}

// ---------------- layer-1 aggregation + ELU + FUSED GEMM2 (act1 never materialized) -------------
// Wave per node. Lane covers feats [2l, 2l+1]. After ELU, 7 per-lane partials vs register W2,
// 6-step butterfly, lanes 0..7 store the 32 B h2 row (pre-scaled by dinv[i], pad col = 0).
__global__ __launch_bounds__(256) void k_agg1(const unsigned* __restrict__ h_u,
    const float* __restrict__ dinv, const int* __restrict__ offs, const int* __restrict__ cnt,
    const uint2* __restrict__ csr, const float* __restrict__ b1,
    const float* __restrict__ W2, float* __restrict__ h2) {
  int i = blockIdx.x * 4 + (threadIdx.x >> 6);   // wave -> node
  int lane = threadIdx.x & 63;                   // lane covers feats [2l, 2l+1]
  if (i >= N_NODES) return;
  float w2a[NCLS], w2b[NCLS];                    // 14 floats, L1-resident after warm-up
#pragma unroll
  for (int c = 0; c < NCLS; c++) {
    w2a[c] = W2[(size_t)(2 * lane) * NCLS + c];
    w2b[c] = W2[(size_t)(2 * lane + 1) * NCLS + c];
  }
  int start = offs[i], len = cnt[i];
  int end = start + len;
  float ax = 0.f, ay = 0.f;
  for (int p = start; p < end; p += 8) {
    uint2 e[8];
#pragma unroll
    for (int k = 0; k < 8; k++) e[k] = csr[p + k];   // padded: safe over-read
    unsigned u[8];
#pragma unroll
    for (int k = 0; k < 8; k++) u[k] = h_u[(size_t)e[k].x * 64 + lane];
#pragma unroll
    for (int k = 0; k < 8; k++) {
      float n = (k == 0 || p + k < end) ? __uint_as_float(e[k].y) : 0.f;
      ax = fmaf(bf_lo(u[k]), n, ax);
      ay = fmaf(bf_hi(u[k]), n, ay);
    }
  }
  float di = dinv[i];
  unsigned u = h_u[(size_t)i * 64 + lane];         // self (already * dinv[i])
  float2 bb = *(const float2*)(b1 + lane * 2);
  float vx = fmaf(di, ax + bf_lo(u), bb.x);
  float vy = fmaf(di, ay + bf_hi(u), bb.y);
  vx = vx > 0.f ? vx : expm1f(vx);                 // ELU (alpha=1)
  vy = vy > 0.f ? vy : expm1f(vy);
  // fused GEMM2: h2[i,:] = dinv[i] * (act1[i,:] @ W2)
  float s[NCLS];
#pragma unroll
  for (int c = 0; c < NCLS; c++) s[c] = fmaf(vy, w2b[c], vx * w2a[c]);
#pragma unroll
  for (int m = 1; m < 64; m <<= 1) {
#pragma unroll
    for (int c = 0; c < NCLS; c++) s[c] += __shfl_xor(s[c], m);
  }
  if (lane < 8) {
    float v = lane == 0 ? s[0] : lane == 1 ? s[1] : lane == 2 ? s[2] :
              lane == 3 ? s[3] : lane == 4 ? s[4] : lane == 5 ? s[5] : s[6];
    h2[(size_t)i * 8 + lane] = (lane < NCLS) ? v * di : 0.f;   // pad col = 0
  }
}

// ---------------- layer-2 aggregation + bias + log_softmax (r0-proven 8-lane/node) ----------------
__global__ __launch_bounds__(256) void k_agg2(const float* __restrict__ h2,
    const float* __restrict__ dinv, const int* __restrict__ offs, const int* __restrict__ cnt,
    const uint2* __restrict__ csr, const float* __restrict__ b2, float* __restrict__ out) {
  int tid = threadIdx.x;
  int i = blockIdx.x * 32 + (tid >> 3);   // 8 lanes per node
  int f = tid & 7;                        // f==7 is padding lane
  if (i >= N_NODES) return;
  int start = offs[i], len = cnt[i];
  int end = start + len;
  float acc = 0.0f;
  for (int p = start; p < end; p += 4) {
    uint2 e0 = csr[p];
    uint2 e1 = csr[p + 1];
    uint2 e2 = csr[p + 2];
    uint2 e3 = csr[p + 3];
    float v0 = h2[(size_t)e0.x * 8 + f];
    float v1 = h2[(size_t)e1.x * 8 + f];
    float v2 = h2[(size_t)e2.x * 8 + f];
    float v3 = h2[(size_t)e3.x * 8 + f];
    float n0 = __uint_as_float(e0.y);
    float n1 = (p + 1 < end) ? __uint_as_float(e1.y) : 0.f;
    float n2 = (p + 2 < end) ? __uint_as_float(e2.y) : 0.f;
    float n3 = (p + 3 < end) ? __uint_as_float(e3.y) : 0.f;
    acc = fmaf(v0, n0, acc);
    acc = fmaf(v1, n1, acc);
    acc = fmaf(v2, n2, acc);
    acc = fmaf(v3, n3, acc);
  }
  float di = dinv[i];
  float v = fmaf(di, acc + h2[(size_t)i * 8 + f], (f < NCLS) ? b2[f] : 0.0f);
  float vm = (f < NCLS) ? v : -INFINITY;
#pragma unroll
  for (int o = 1; o < 8; o <<= 1) vm = fmaxf(vm, __shfl_xor(vm, o, 8));
  float ex = (f < NCLS) ? expf(v - vm) : 0.0f;
  float s8 = ex;
#pragma unroll
  for (int o = 1; o < 8; o <<= 1) s8 += __shfl_xor(s8, o, 8);
  float lse = logf(s8);
  if (f < NCLS) out[(size_t)i * NCLS + f] = v - vm - lse;
}

// ---------------- launch ----------------
extern "C" void kernel_launch(void* const* d_in, const int* in_sizes, int n_in,
                              void* d_out, int out_size, void* d_ws, size_t ws_size,
                              hipStream_t stream) {
  const float* x  = (const float*)d_in[0];
  const int*   ei = (const int*)d_in[1];
  const float* ew = (const float*)d_in[2];
  const float* W1 = (const float*)d_in[3];
  const float* b1 = (const float*)d_in[4];
  const float* W2 = (const float*)d_in[5];
  const float* b2 = (const float*)d_in[6];
  float* out = (float*)d_out;

  char* w = (char*)d_ws;
  const size_t Npad  = ((size_t)N_NODES * 4 + 255) & ~(size_t)255;
  const size_t Npad8 = ((size_t)N_NODES * 8 + 255) & ~(size_t)255;
  const size_t Epad  = ((size_t)N_EDGES * 4 + 255) & ~(size_t)255;
  size_t off = 0;
  unsigned long long* packed = (unsigned long long*)(w + off); off += Npad8;  // zeroed
  float*    dinv     = (float*)(w + off);    off += Npad;
  int*      cnt      = (int*)(w + off);      off += Npad;
  int*      offs     = (int*)(w + off);      off += Npad;
  int*      bsum     = (int*)(w + off);      off += 1024;
  int*      rank     = (int*)(w + off);      off += Epad;
  uint2*    csr      = (uint2*)(w + off);    off += ((size_t)(N_EDGES + 8) * 8 + 255) & ~(size_t)255;
  uint4*    w1bf     = (uint4*)(w + off);    off += (size_t)8192 * 16;        // 128 KB
  uint4*    xbf      = (uint4*)(w + off);    off += (size_t)6256 * 1024 * 16; // 102.5 MB (padded)
  unsigned short* h_u16 = (unsigned short*)(w + off); off += (size_t)N_NODES * HID * 2;
  float*    h2       = (float*)(w + off);    off += (size_t)N_NODES * 8 * 4;

  hipMemsetAsync(packed, 0, Npad8, stream);

  k_degconv<<<G_DEGCONV, 256, 0, stream>>>(ei, ew, packed, rank, x, xbf);
  k_mid<<<NB_SCAN + 32, 256, 0, stream>>>(packed, dinv, cnt, bsum, W1, w1bf, csr + N_EDGES);
  k_scan_final<<<NB_SCAN, 256, 0, stream>>>(cnt, bsum, offs);
  k_fillgemm<<<G2, 512, 0, stream>>>(ei, ew, rank, offs, csr, xbf, w1bf, dinv, h_u16);
  k_agg1<<<(N_NODES + 3) / 4, 256, 0, stream>>>((const unsigned*)h_u16, dinv, offs, cnt,
                                                csr, b1, W2, h2);
  k_agg2<<<N_NODES / 32, 256, 0, stream>>>(h2, dinv, offs, cnt, csr, b2, out);
}